// Round 1
// baseline (507.366 us; speedup 1.0000x reference)
//
#include <hip/hip_runtime.h>
#include <hip/hip_bf16.h>

// SoftTimeAttention: out[b,k,:] = sum_j softmax_j(-(T*(t[b,k]-t[b,j]))^2) * h[b,j,:]
// B=4, T=4096, H=256, f32 in/out. Max logit is 0 (j==k), so softmax needs no max pass.

constexpr int Bb = 4;
constexpr int Tt = 4096;
constexpr int Hh = 256;
constexpr int QB = 64;          // queries per block
constexpr int JB = 64;          // keys per tile
constexpr int NT = Tt / JB;     // 64 tiles
constexpr int NTHREADS = 512;   // 8 waves

__device__ __forceinline__ void gld16(const float* g, float* l) {
    __builtin_amdgcn_global_load_lds(
        (const __attribute__((address_space(1))) void*)g,
        (__attribute__((address_space(3))) void*)l, 16, 0, 0);
}
__device__ __forceinline__ void gld4(const float* g, float* l) {
    __builtin_amdgcn_global_load_lds(
        (const __attribute__((address_space(1))) void*)g,
        (__attribute__((address_space(3))) void*)l, 4, 0, 0);
}

__global__ __launch_bounds__(NTHREADS, 2) void stattn_kernel(
    const float* __restrict__ h_seq,
    const float* __restrict__ tvals,
    float* __restrict__ out)
{
    __shared__ float hbuf[2][JB][Hh];   // 128 KB, double-buffered h tile
    __shared__ float wbuf[JB][QB];      // 16 KB weight tile, [j][q]
    __shared__ float tjbuf[2][JB];      // t values of current/next key tile
    __shared__ float sden[QB];          // softmax denominators (accumulated)
    __shared__ float tqs[QB];           // t values of this block's queries

    const int tid  = threadIdx.x;
    const int lane = tid & 63;
    const int wv   = tid >> 6;          // wave id 0..7

    // XCD-contiguous swizzle: 256 blocks round-robin over 8 XCDs; make each XCD
    // serve a contiguous run of 32 logical blocks => one batch per 2 XCDs,
    // so the 4 MB per-batch h panel stays resident in that XCD's L2.
    const int phys = blockIdx.x;
    const int lb   = (phys & 7) * 32 + (phys >> 3);
    const int b    = lb >> 6;           // batch
    const int qt   = lb & 63;           // query tile within batch
    const int q0   = qt * QB;

    const float* hb = h_seq + (size_t)b * Tt * Hh;
    const float* tb = tvals + (size_t)b * Tt;

    if (tid < QB) { tqs[tid] = tb[q0 + tid]; sden[tid] = 0.0f; }

    float acc[8][4];
    #pragma unroll
    for (int k = 0; k < 8; ++k)
        #pragma unroll
        for (int c = 0; c < 4; ++c) acc[k][c] = 0.0f;

    const float Tf = (float)Tt;

    auto stage = [&](int buf, int tile) {
        // 64 KB contiguous chunk: h rows [tile*JB, tile*JB+JB)
        const float* src = hb + (size_t)tile * JB * Hh;
        float* dst = &hbuf[buf][0][0];
        #pragma unroll
        for (int i = 0; i < 8; ++i) {
            const int off = i * (NTHREADS * 4) + tid * 4;   // float index
            gld16(src + off, dst + off);
        }
        // t values for this key tile; every wave loads all 64 redundantly so
        // per-wave vmcnt accounting stays uniform (benign same-value overwrite).
        gld4(tb + tile * JB + lane, &tjbuf[buf][lane]);
    };

    stage(0, 0);
    __syncthreads();   // prologue: tqs/sden visible; stage(0) drained

    const int qw = wv * 8;              // wave's first local query

    for (int t = 0; t < NT; ++t) {
        const int cur = t & 1;

        // Rendezvous A: every wave's stage(t) loads complete (vmcnt(0) is part
        // of __syncthreads). Also orders: main(t-1) done before wbuf overwrite.
        __syncthreads();

        // ---- weight phase: w[j][q] for tile t, plus denominator partials
        {
            const int q  = tid & 63;
            const int jg = tid >> 6;     // 0..7 -> 8 consecutive j each
            const float tq = tqs[q];
            const float4 tj0 = *(const float4*)&tjbuf[cur][jg * 8];
            const float4 tj1 = *(const float4*)&tjbuf[cur][jg * 8 + 4];
            const float tjv[8] = {tj0.x, tj0.y, tj0.z, tj0.w,
                                  tj1.x, tj1.y, tj1.z, tj1.w};
            float part = 0.0f;
            #pragma unroll
            for (int jj = 0; jj < 8; ++jj) {
                const float d = Tf * (tq - tjv[jj]);
                const float w = __expf(-d * d);
                wbuf[jg * 8 + jj][q] = w;
                part += w;
            }
            atomicAdd(&sden[q], part);
        }

        // ---- prefetch next h tile (overlaps with main loop below; the raw
        // barrier does NOT drain vmcnt, so these stay in flight)
        if (t + 1 < NT) stage((t + 1) & 1, t + 1);

        // Rendezvous B: wbuf writes + sden atomics visible; prefetch NOT drained.
        asm volatile("s_waitcnt lgkmcnt(0)" ::: "memory");
        __builtin_amdgcn_s_barrier();
        asm volatile("" ::: "memory");

        // ---- main: acc[k][c] += w[j][qw+k] * h[j][lane*4+c]
        #pragma unroll 2
        for (int j = 0; j < JB; ++j) {
            const float4 hv = *(const float4*)&hbuf[cur][j][lane * 4];
            const float4 w0 = *(const float4*)&wbuf[j][qw];
            const float4 w1 = *(const float4*)&wbuf[j][qw + 4];
            const float wr[8] = {w0.x, w0.y, w0.z, w0.w,
                                 w1.x, w1.y, w1.z, w1.w};
            #pragma unroll
            for (int k = 0; k < 8; ++k) {
                acc[k][0] += wr[k] * hv.x;
                acc[k][1] += wr[k] * hv.y;
                acc[k][2] += wr[k] * hv.z;
                acc[k][3] += wr[k] * hv.w;
            }
        }
    }

    // Last wphase's atomics were followed by rendezvous B, and each wave's own
    // acc is private => safe to finalize without another barrier.
    #pragma unroll
    for (int k = 0; k < 8; ++k) {
        const int q = q0 + qw + k;
        const float inv = 1.0f / sden[qw + k];
        float4 o;
        o.x = acc[k][0] * inv;
        o.y = acc[k][1] * inv;
        o.z = acc[k][2] * inv;
        o.w = acc[k][3] * inv;
        *(float4*)&out[((size_t)b * Tt + q) * Hh + (size_t)(lane * 4)] = o;
    }
}

extern "C" void kernel_launch(void* const* d_in, const int* in_sizes, int n_in,
                              void* d_out, int out_size, void* d_ws, size_t ws_size,
                              hipStream_t stream) {
    const float* h_seq = (const float*)d_in[0];
    const float* tvals = (const float*)d_in[1];
    float* out = (float*)d_out;
    dim3 grid(Bb * (Tt / QB));   // 256 blocks
    dim3 block(NTHREADS);
    stattn_kernel<<<grid, block, 0, stream>>>(h_seq, tvals, out);
}

// Round 2
// 87.572 us; speedup vs baseline: 5.7937x; 5.7937x over previous
//
#include <hip/hip_runtime.h>
#include <hip/hip_bf16.h>

// SoftTimeAttention: out[b,q,:] = sum_j softmax_j(-(T*(t_q-t_j))^2) * h[b,j,:]
// B=4, T=4096, H=256, f32 in/out. Max logit is 0 (at j==q) -> no max pass needed.
//
// MFMA version: W (weights) computed on the fly in A-fragment register layout,
// H pre-converted to bf16 and transposed into ws as hT[b][h][j] so B-fragments
// are contiguous ds_read_b128 from a swizzled LDS tile.

constexpr int Bb = 4;
constexpr int Tt = 4096;
constexpr int Hh = 256;
constexpr int QB = 64;            // queries per block
constexpr int KSTEP = 64;         // j per K-iteration
constexpr int NKT = Tt / KSTEP;   // 64
constexpr int NTHREADS = 512;     // 8 waves

typedef __attribute__((ext_vector_type(8))) short short8;
typedef __attribute__((ext_vector_type(8))) unsigned short ushort8;
typedef __attribute__((ext_vector_type(4))) float f32x4;

__device__ __forceinline__ void gld16(const void* g, void* l) {
    __builtin_amdgcn_global_load_lds(
        (const __attribute__((address_space(1))) void*)g,
        (__attribute__((address_space(3))) void*)l, 16, 0, 0);
}
__device__ __forceinline__ void gld4(const void* g, void* l) {
    __builtin_amdgcn_global_load_lds(
        (const __attribute__((address_space(1))) void*)g,
        (__attribute__((address_space(3))) void*)l, 4, 0, 0);
}

__device__ __forceinline__ unsigned short f2bf(float f) {
    union { __hip_bfloat16 b; unsigned short u; } cv;
    cv.b = __float2bfloat16(f);   // RNE
    return cv.u;
}

// ---------------------------------------------------------------------------
// Pre-pass: hT[b][h][j] = bf16(h_seq[b][j][h]).  64(j) x 64(h) tiles via LDS.
__global__ __launch_bounds__(512) void transpose_cvt_kernel(
    const float* __restrict__ h_seq, unsigned short* __restrict__ hT)
{
    __shared__ float tile[64][65];
    const int bidx = blockIdx.x;        // b*256 + jt*4 + ht
    const int b  = bidx >> 8;
    const int jt = (bidx >> 2) & 63;
    const int ht = bidx & 3;
    const int j0 = jt * 64, h0 = ht * 64;

    const int r  = threadIdx.x >> 3;        // 0..63
    const int c8 = (threadIdx.x & 7) * 8;   // 0..56

    const float* src = h_seq + ((size_t)b * Tt + j0) * Hh + h0;
    float4 v0 = *(const float4*)&src[r * Hh + c8];
    float4 v1 = *(const float4*)&src[r * Hh + c8 + 4];
    tile[r][c8 + 0] = v0.x; tile[r][c8 + 1] = v0.y;
    tile[r][c8 + 2] = v0.z; tile[r][c8 + 3] = v0.w;
    tile[r][c8 + 4] = v1.x; tile[r][c8 + 5] = v1.y;
    tile[r][c8 + 6] = v1.z; tile[r][c8 + 7] = v1.w;
    __syncthreads();

    ushort8 o;
    #pragma unroll
    for (int i = 0; i < 8; ++i) o[i] = f2bf(tile[c8 + i][r]);
    *(ushort8*)&hT[((size_t)b * Hh + h0 + r) * Tt + j0 + c8] = o;
}

// ---------------------------------------------------------------------------
// Main MFMA kernel. Block: 64q x 256h. 8 waves = 2(q) x 4(h); wave 32q x 64h.
__global__ __launch_bounds__(NTHREADS, 2) void stattn_mfma(
    const unsigned short* __restrict__ hT,
    const float* __restrict__ tvals,
    float* __restrict__ out)
{
    // hbuf row = 64 ushorts (128 B) = 8 slots of 16 B; slot XOR-swizzled by h&7
    __shared__ unsigned short hbuf[2][Hh * KSTEP];  // 64 KB
    __shared__ float tjs[Tt];                       // 16 KB, pre-scaled t*T
    __shared__ float den_l[QB];

    const int tid  = threadIdx.x;
    const int lane = tid & 63;
    const int wv   = tid >> 6;
    const int wm   = wv >> 2;        // 0..1 (q half)
    const int wn   = wv & 3;         // 0..3 (h quarter)

    // XCD-contiguous swizzle: each XCD serves one contiguous run of 32 blocks
    const int phys = blockIdx.x;
    const int lb   = (phys & 7) * 32 + (phys >> 3);
    const int b    = lb >> 6;
    const int qt   = lb & 63;
    const int q0   = qt * QB;

    const unsigned short* hTb = hT + (size_t)b * Hh * Tt;
    const float* tb = tvals + (size_t)b * Tt;
    const float Tf = (float)Tt;

    for (int i = tid; i < Tt; i += NTHREADS) tjs[i] = Tf * tb[i];

    float tqv[2];
    tqv[0] = Tf * tb[q0 + wm * 32 + (lane & 15)];
    tqv[1] = Tf * tb[q0 + wm * 32 + 16 + (lane & 15)];

    auto stage = [&](int buf, int t) {
        const unsigned short* src = hTb + t * KSTEP;     // row h: +h*Tt
        unsigned short* dst = &hbuf[buf][0];
        #pragma unroll
        for (int rnd = 0; rnd < 4; ++rnd) {
            const int o16  = rnd * NTHREADS + tid;   // 16-B unit index, 0..2047
            const int h    = o16 >> 3;
            const int slot = o16 & 7;
            const int c    = slot ^ (h & 7);         // data chunk held by this slot
            gld16(src + (size_t)h * Tt + c * 8, dst + o16 * 8);
        }
    };

    f32x4 acc[2][4];
    #pragma unroll
    for (int m = 0; m < 2; ++m)
        #pragma unroll
        for (int n = 0; n < 4; ++n) acc[m][n] = 0.0f;
    float den0 = 0.0f, den1 = 0.0f;

    stage(0, 0);

    for (int t = 0; t < NKT; ++t) {
        const int cur = t & 1;
        __syncthreads();   // stage(t) drained (vmcnt0); prev iter LDS reads done

        if (t + 1 < NKT) stage(cur ^ 1, t + 1);   // in flight across this iter

        // ---- A-frags: w[q][j] in MFMA A layout: row=lane&15, k=(lane>>4)*8+i
        short8 afr[2][2];   // [m][kc]
        {
            const int jb0 = t * KSTEP + ((lane >> 4) << 3);
            #pragma unroll
            for (int kc = 0; kc < 2; ++kc) {
                const int jb = jb0 + kc * 32;
                const float4 ta = *(const float4*)&tjs[jb];
                const float4 tc = *(const float4*)&tjs[jb + 4];
                const float tj8[8] = {ta.x, ta.y, ta.z, ta.w,
                                      tc.x, tc.y, tc.z, tc.w};
                #pragma unroll
                for (int m = 0; m < 2; ++m) {
                    const float tq = tqv[m];
                    float w[8];
                    float s = 0.0f;
                    #pragma unroll
                    for (int i = 0; i < 8; ++i) {
                        const float d = tq - tj8[i];
                        w[i] = __expf(-d * d);
                        s += w[i];
                    }
                    if (m == 0) den0 += s; else den1 += s;
                    short8 a;
                    #pragma unroll
                    for (int i = 0; i < 8; ++i) a[i] = (short)f2bf(w[i]);
                    afr[m][kc] = a;
                }
            }
        }

        // ---- MFMA phase: B-frags from swizzled LDS, 16 mfma per iter
        const unsigned short* hb_l = &hbuf[cur][0];
        const int hbase = wn * 64 + (lane & 15);
        const int cbase = (lane >> 4);
        #pragma unroll
        for (int n = 0; n < 4; ++n) {
            const int hloc = hbase + n * 16;
            #pragma unroll
            for (int kc = 0; kc < 2; ++kc) {
                const int c    = kc * 4 + cbase;
                const int slot = c ^ (hloc & 7);
                const short8 bf = *(const short8*)&hb_l[hloc * 64 + slot * 8];
                acc[0][n] = __builtin_amdgcn_mfma_f32_16x16x32_bf16(
                    afr[0][kc], bf, acc[0][n], 0, 0, 0);
                acc[1][n] = __builtin_amdgcn_mfma_f32_16x16x32_bf16(
                    afr[1][kc], bf, acc[1][n], 0, 0, 0);
            }
        }
    }

    // ---- denominators: complete row sums (chunks live in lanes r,r+16,r+32,r+48)
    den0 += __shfl_xor(den0, 16); den0 += __shfl_xor(den0, 32);
    den1 += __shfl_xor(den1, 16); den1 += __shfl_xor(den1, 32);
    if (lane < 16) {
        den_l[wm * 32 + lane]      = den0;   // q-row = lane&15 (replicated x4)
        den_l[wm * 32 + 16 + lane] = den1;
    }
    __syncthreads();

    // ---- C write: D row=(lane>>4)*4+reg, col=lane&15
    #pragma unroll
    for (int m = 0; m < 2; ++m) {
        #pragma unroll
        for (int r = 0; r < 4; ++r) {
            const int ql = wm * 32 + m * 16 + (lane >> 4) * 4 + r;
            const float inv = 1.0f / den_l[ql];
            const int qg = q0 + ql;
            float* orow = out + ((size_t)b * Tt + qg) * Hh + wn * 64 + (lane & 15);
            #pragma unroll
            for (int n = 0; n < 4; ++n) orow[n * 16] = acc[m][n][r] * inv;
        }
    }
}

// ---------------------------------------------------------------------------
// Fallback (round-1 proven f32 kernel) if ws is too small for hT.
constexpr int JB = 64;
constexpr int NT = Tt / JB;

__global__ __launch_bounds__(NTHREADS, 2) void stattn_kernel(
    const float* __restrict__ h_seq,
    const float* __restrict__ tvals,
    float* __restrict__ out)
{
    __shared__ float hbuf[2][JB][Hh];
    __shared__ float wbuf[JB][QB];
    __shared__ float tjbuf[2][JB];
    __shared__ float sden[QB];
    __shared__ float tqs[QB];

    const int tid  = threadIdx.x;
    const int lane = tid & 63;
    const int wv   = tid >> 6;
    const int phys = blockIdx.x;
    const int lb   = (phys & 7) * 32 + (phys >> 3);
    const int b    = lb >> 6;
    const int qt   = lb & 63;
    const int q0   = qt * QB;

    const float* hb = h_seq + (size_t)b * Tt * Hh;
    const float* tb = tvals + (size_t)b * Tt;

    if (tid < QB) { tqs[tid] = tb[q0 + tid]; sden[tid] = 0.0f; }

    float acc[8][4];
    #pragma unroll
    for (int k = 0; k < 8; ++k)
        #pragma unroll
        for (int c = 0; c < 4; ++c) acc[k][c] = 0.0f;

    const float Tf = (float)Tt;

    auto stage = [&](int buf, int tile) {
        const float* src = hb + (size_t)tile * JB * Hh;
        float* dst = &hbuf[buf][0][0];
        #pragma unroll
        for (int i = 0; i < 8; ++i) {
            const int off = i * (NTHREADS * 4) + tid * 4;
            gld16(src + off, dst + off);
        }
        gld4(tb + tile * JB + lane, &tjbuf[buf][lane]);
    };

    stage(0, 0);
    __syncthreads();

    const int qw = wv * 8;

    for (int t = 0; t < NT; ++t) {
        const int cur = t & 1;
        __syncthreads();
        {
            const int q  = tid & 63;
            const int jg = tid >> 6;
            const float tq = tqs[q];
            const float4 tj0 = *(const float4*)&tjbuf[cur][jg * 8];
            const float4 tj1 = *(const float4*)&tjbuf[cur][jg * 8 + 4];
            const float tjv[8] = {tj0.x, tj0.y, tj0.z, tj0.w,
                                  tj1.x, tj1.y, tj1.z, tj1.w};
            float part = 0.0f;
            #pragma unroll
            for (int jj = 0; jj < 8; ++jj) {
                const float d = Tf * (tq - tjv[jj]);
                const float w = __expf(-d * d);
                wbuf[jg * 8 + jj][q] = w;
                part += w;
            }
            atomicAdd(&sden[q], part);
        }
        if (t + 1 < NT) stage((t + 1) & 1, t + 1);
        asm volatile("s_waitcnt lgkmcnt(0)" ::: "memory");
        __builtin_amdgcn_s_barrier();
        asm volatile("" ::: "memory");
        #pragma unroll 2
        for (int j = 0; j < JB; ++j) {
            const float4 hv = *(const float4*)&hbuf[cur][j][lane * 4];
            const float4 w0 = *(const float4*)&wbuf[j][qw];
            const float4 w1 = *(const float4*)&wbuf[j][qw + 4];
            const float wr[8] = {w0.x, w0.y, w0.z, w0.w,
                                 w1.x, w1.y, w1.z, w1.w};
            #pragma unroll
            for (int k = 0; k < 8; ++k) {
                acc[k][0] += wr[k] * hv.x;
                acc[k][1] += wr[k] * hv.y;
                acc[k][2] += wr[k] * hv.z;
                acc[k][3] += wr[k] * hv.w;
            }
        }
    }

    #pragma unroll
    for (int k = 0; k < 8; ++k) {
        const int q = q0 + qw + k;
        const float inv = 1.0f / sden[qw + k];
        float4 o;
        o.x = acc[k][0] * inv;
        o.y = acc[k][1] * inv;
        o.z = acc[k][2] * inv;
        o.w = acc[k][3] * inv;
        *(float4*)&out[((size_t)b * Tt + q) * Hh + (size_t)(lane * 4)] = o;
    }
}

extern "C" void kernel_launch(void* const* d_in, const int* in_sizes, int n_in,
                              void* d_out, int out_size, void* d_ws, size_t ws_size,
                              hipStream_t stream) {
    const float* h_seq = (const float*)d_in[0];
    const float* tvals = (const float*)d_in[1];
    float* out = (float*)d_out;

    const size_t need = (size_t)Bb * Hh * Tt * sizeof(unsigned short);  // 8.4 MB
    if (ws_size >= need) {
        unsigned short* hT = (unsigned short*)d_ws;
        transpose_cvt_kernel<<<dim3(Bb * 256), dim3(512), 0, stream>>>(h_seq, hT);
        stattn_mfma<<<dim3(Bb * (Tt / QB)), dim3(NTHREADS), 0, stream>>>(hT, tvals, out);
    } else {
        stattn_kernel<<<dim3(Bb * (Tt / QB)), dim3(NTHREADS), 0, stream>>>(h_seq, tvals, out);
    }
}

// Round 3
// 23.614 us; speedup vs baseline: 21.4859x; 3.7085x over previous
//
#include <hip/hip_runtime.h>
#include <hip/hip_bf16.h>

// SoftTimeAttention: out[b,q,:] = sum_j softmax_j(-(T*(t_q-t_j))^2) * h[b,j,:]
// B=4, T=4096, H=256, f32. Key fact: w = exp(-(4096*dt)^2) is exactly 0 in f32
// for |dt| > ~0.0023, so each query interacts with ~19 keys. Bucket-sort t,
// process queries in sorted order with a sliding candidate window.

constexpr int Bb = 4;
constexpr int Tt = 4096;
constexpr int Hh = 256;
constexpr int NB = 1024;          // t-buckets per batch (width ~9.77e-4)
// bucket distance >= 3 => dt > 2/1024 => x > 8 => w < e^-64: negligible.

// ---------------------------------------------------------------------------
// Per-batch counting sort of t into NB buckets. One block (1024 thr) per batch.
__global__ __launch_bounds__(1024) void sort_kernel(
    const float* __restrict__ tvals,
    float* __restrict__ sorted_t,
    int* __restrict__ sorted_idx,
    int* __restrict__ offsets)      // [B][NB+1] exclusive bucket starts
{
    __shared__ int hist[NB];
    __shared__ int excl[NB];
    __shared__ int cnt[NB];
    __shared__ int wsum[16];
    __shared__ int wexcl[16];

    const int b   = blockIdx.x;
    const int tid = threadIdx.x;
    const int lane = tid & 63;
    const int wv   = tid >> 6;
    const float* tb = tvals + (size_t)b * Tt;

    hist[tid] = 0;
    cnt[tid]  = 0;
    __syncthreads();

    float tv[4]; int bk[4];
    #pragma unroll
    for (int i = 0; i < 4; ++i) {
        const int j = i * 1024 + tid;
        const float t = tb[j];
        int k = (int)(t * (float)NB);
        k = k < 0 ? 0 : (k > NB - 1 ? NB - 1 : k);
        tv[i] = t; bk[i] = k;
        atomicAdd(&hist[k], 1);
    }
    __syncthreads();

    // inclusive scan over NB=1024 buckets: wave scan + cross-wave fixup
    const int self = hist[tid];
    int x = self;
    #pragma unroll
    for (int d = 1; d < 64; d <<= 1) {
        const int y = __shfl_up(x, d);
        if (lane >= d) x += y;
    }
    if (lane == 63) wsum[wv] = x;
    __syncthreads();
    if (tid < 16) {
        int y = wsum[tid];
        #pragma unroll
        for (int d = 1; d < 16; d <<= 1) {
            const int z = __shfl_up(y, d);
            if (tid >= d) y += z;
        }
        wexcl[tid] = y - wsum[tid];
    }
    __syncthreads();
    const int incl = x + wexcl[wv];
    excl[tid] = incl - self;
    offsets[(size_t)b * (NB + 1) + tid] = incl - self;
    if (tid == 0) offsets[(size_t)b * (NB + 1) + NB] = Tt;
    __syncthreads();

    #pragma unroll
    for (int i = 0; i < 4; ++i) {
        const int k = bk[i];
        const int rank = atomicAdd(&cnt[k], 1);
        const int pos = excl[k] + rank;
        sorted_t[(size_t)b * Tt + pos]   = tv[i];
        sorted_idx[(size_t)b * Tt + pos] = i * 1024 + tid;
    }
}

// ---------------------------------------------------------------------------
// Main sparse kernel: 256 thr = 4 waves; each wave handles 4 consecutive
// sorted queries (shared candidate window). Grid = B * T/16 = 1024 blocks.
constexpr int QPW = 4;
constexpr int MTHREADS = 256;

__global__ __launch_bounds__(MTHREADS) void stattn_sparse(
    const float* __restrict__ h_seq,
    const float* __restrict__ sorted_t,
    const int* __restrict__ sorted_idx,
    const int* __restrict__ offsets,
    float* __restrict__ out)
{
    const int tid  = threadIdx.x;
    const int lane = tid & 63;
    const int wv   = tid >> 6;

    // XCD-contiguous swizzle (1024 blocks = 8 XCDs x 128): 2 XCDs per batch,
    // so the 4 MB per-batch h panel stays L2-resident.
    const int phys = blockIdx.x;
    const int lb   = (phys & 7) * 128 + (phys >> 3);
    const int b    = lb >> 8;
    const int blk  = lb & 255;

    const float* st = sorted_t  + (size_t)b * Tt;
    const int*   si = sorted_idx + (size_t)b * Tt;
    const int*   off = offsets + (size_t)b * (NB + 1);
    const float* hb = h_seq + (size_t)b * Tt * Hh;
    const float Tf = (float)Tt;

    const int p0 = blk * 16 + wv * QPW;

    float tq[QPW]; int qi[QPW];
    #pragma unroll
    for (int g = 0; g < QPW; ++g) { tq[g] = st[p0 + g]; qi[g] = si[p0 + g]; }

    // group candidate window: buckets are nondecreasing along sorted positions
    int bmin = (int)(tq[0] * (float)NB);
    int bmax = (int)(tq[QPW - 1] * (float)NB);
    bmin = bmin < 0 ? 0 : (bmin > NB - 1 ? NB - 1 : bmin);
    bmax = bmax < 0 ? 0 : (bmax > NB - 1 ? NB - 1 : bmax);
    const int blo = bmin - 2 < 0 ? 0 : bmin - 2;
    const int bhi = bmax + 3 > NB ? NB : bmax + 3;
    const int lo = off[blo];
    const int hi = off[bhi];

    float4 acc[QPW];
    float  den[QPW];
    #pragma unroll
    for (int g = 0; g < QPW; ++g) {
        acc[g] = make_float4(0.f, 0.f, 0.f, 0.f);
        den[g] = 0.f;
    }

    for (int base = lo; base < hi; base += 64) {
        const int p = base + lane;
        const bool valid = p < hi;
        const float tj = valid ? st[p] : 1e9f;    // dummy -> w == 0 exactly
        const int   jj = valid ? si[p] : 0;

        float w[QPW]; float wmax = 0.f;
        #pragma unroll
        for (int g = 0; g < QPW; ++g) {
            const float x = Tf * (tq[g] - tj);
            w[g] = __expf(-x * x);
            den[g] += w[g];
            wmax = fmaxf(wmax, w[g]);
        }

        unsigned long long mask = __ballot(wmax > 1e-20f);
        while (mask) {
            const int s0 = __builtin_ctzll(mask); mask &= mask - 1;
            const bool has2 = mask != 0;
            const int s1 = has2 ? __builtin_ctzll(mask) : s0;
            if (has2) mask &= mask - 1;

            const int j0 = __shfl(jj, s0);
            const int j1 = __shfl(jj, s1);
            const float4 h0 = *(const float4*)&hb[(size_t)j0 * Hh + lane * 4];
            const float4 h1 = *(const float4*)&hb[(size_t)j1 * Hh + lane * 4];

            #pragma unroll
            for (int g = 0; g < QPW; ++g) {
                const float a0 = __shfl(w[g], s0);
                float a1 = __shfl(w[g], s1);
                if (!has2) a1 = 0.f;             // wave-uniform
                acc[g].x += a0 * h0.x; acc[g].x += a1 * h1.x;
                acc[g].y += a0 * h0.y; acc[g].y += a1 * h1.y;
                acc[g].z += a0 * h0.z; acc[g].z += a1 * h1.z;
                acc[g].w += a0 * h0.w; acc[g].w += a1 * h1.w;
            }
        }
    }

    // reduce denominators across lanes
    #pragma unroll
    for (int g = 0; g < QPW; ++g) {
        float d = den[g];
        #pragma unroll
        for (int s = 1; s < 64; s <<= 1) d += __shfl_xor(d, s);
        den[g] = d;
    }

    #pragma unroll
    for (int g = 0; g < QPW; ++g) {
        const float inv = 1.0f / den[g];
        float* orow = out + ((size_t)b * Tt + qi[g]) * Hh + lane * 4;
        float4 o;
        o.x = acc[g].x * inv; o.y = acc[g].y * inv;
        o.z = acc[g].z * inv; o.w = acc[g].w * inv;
        *(float4*)orow = o;
    }
}

// ---------------------------------------------------------------------------
// Fallback dense f32 kernel (round-1 proven) if ws is too small.
constexpr int QB = 64;
constexpr int JB = 64;
constexpr int NT = Tt / JB;
constexpr int NTHREADS = 512;

__device__ __forceinline__ void gld16(const void* g, void* l) {
    __builtin_amdgcn_global_load_lds(
        (const __attribute__((address_space(1))) void*)g,
        (__attribute__((address_space(3))) void*)l, 16, 0, 0);
}
__device__ __forceinline__ void gld4(const void* g, void* l) {
    __builtin_amdgcn_global_load_lds(
        (const __attribute__((address_space(1))) void*)g,
        (__attribute__((address_space(3))) void*)l, 4, 0, 0);
}

__global__ __launch_bounds__(NTHREADS, 2) void stattn_kernel(
    const float* __restrict__ h_seq,
    const float* __restrict__ tvals,
    float* __restrict__ out)
{
    __shared__ float hbuf[2][JB][Hh];
    __shared__ float wbuf[JB][QB];
    __shared__ float tjbuf[2][JB];
    __shared__ float sden[QB];
    __shared__ float tqs[QB];

    const int tid  = threadIdx.x;
    const int lane = tid & 63;
    const int wv   = tid >> 6;
    const int phys = blockIdx.x;
    const int lb   = (phys & 7) * 32 + (phys >> 3);
    const int b    = lb >> 6;
    const int qt   = lb & 63;
    const int q0   = qt * QB;

    const float* hb = h_seq + (size_t)b * Tt * Hh;
    const float* tb = tvals + (size_t)b * Tt;

    if (tid < QB) { tqs[tid] = tb[q0 + tid]; sden[tid] = 0.0f; }

    float acc[8][4];
    #pragma unroll
    for (int k = 0; k < 8; ++k)
        #pragma unroll
        for (int c = 0; c < 4; ++c) acc[k][c] = 0.0f;

    const float Tf = (float)Tt;

    auto stage = [&](int buf, int tile) {
        const float* src = hb + (size_t)tile * JB * Hh;
        float* dst = &hbuf[buf][0][0];
        #pragma unroll
        for (int i = 0; i < 8; ++i) {
            const int off = i * (NTHREADS * 4) + tid * 4;
            gld16(src + off, dst + off);
        }
        gld4(tb + tile * JB + lane, &tjbuf[buf][lane]);
    };

    stage(0, 0);
    __syncthreads();

    const int qw = wv * 8;

    for (int t = 0; t < NT; ++t) {
        const int cur = t & 1;
        __syncthreads();
        {
            const int q  = tid & 63;
            const int jg = tid >> 6;
            const float tq = tqs[q];
            const float4 tj0 = *(const float4*)&tjbuf[cur][jg * 8];
            const float4 tj1 = *(const float4*)&tjbuf[cur][jg * 8 + 4];
            const float tjv[8] = {tj0.x, tj0.y, tj0.z, tj0.w,
                                  tj1.x, tj1.y, tj1.z, tj1.w};
            float part = 0.0f;
            #pragma unroll
            for (int jj = 0; jj < 8; ++jj) {
                const float d = Tf * (tq - tjv[jj]);
                const float w = __expf(-d * d);
                wbuf[jg * 8 + jj][q] = w;
                part += w;
            }
            atomicAdd(&sden[q], part);
        }
        if (t + 1 < NT) stage((t + 1) & 1, t + 1);
        asm volatile("s_waitcnt lgkmcnt(0)" ::: "memory");
        __builtin_amdgcn_s_barrier();
        asm volatile("" ::: "memory");
        #pragma unroll 2
        for (int j = 0; j < JB; ++j) {
            const float4 hv = *(const float4*)&hbuf[cur][j][lane * 4];
            const float4 w0 = *(const float4*)&wbuf[j][qw];
            const float4 w1 = *(const float4*)&wbuf[j][qw + 4];
            const float wr[8] = {w0.x, w0.y, w0.z, w0.w,
                                 w1.x, w1.y, w1.z, w1.w};
            #pragma unroll
            for (int k = 0; k < 8; ++k) {
                acc[k][0] += wr[k] * hv.x;
                acc[k][1] += wr[k] * hv.y;
                acc[k][2] += wr[k] * hv.z;
                acc[k][3] += wr[k] * hv.w;
            }
        }
    }

    #pragma unroll
    for (int k = 0; k < 8; ++k) {
        const int q = q0 + qw + k;
        const float inv = 1.0f / sden[qw + k];
        float4 o;
        o.x = acc[k][0] * inv;
        o.y = acc[k][1] * inv;
        o.z = acc[k][2] * inv;
        o.w = acc[k][3] * inv;
        *(float4*)&out[((size_t)b * Tt + q) * Hh + (size_t)(lane * 4)] = o;
    }
}

extern "C" void kernel_launch(void* const* d_in, const int* in_sizes, int n_in,
                              void* d_out, int out_size, void* d_ws, size_t ws_size,
                              hipStream_t stream) {
    const float* h_seq = (const float*)d_in[0];
    const float* tvals = (const float*)d_in[1];
    float* out = (float*)d_out;

    // ws layout: sorted_t (B*T f32) | sorted_idx (B*T i32) | offsets (B*(NB+1) i32)
    const size_t need = (size_t)Bb * Tt * 4 * 2 + (size_t)Bb * (NB + 1) * 4;
    if (ws_size >= need) {
        float* sorted_t   = (float*)d_ws;
        int*   sorted_idx = (int*)(sorted_t + (size_t)Bb * Tt);
        int*   offsets    = (int*)(sorted_idx + (size_t)Bb * Tt);
        sort_kernel<<<dim3(Bb), dim3(1024), 0, stream>>>(
            tvals, sorted_t, sorted_idx, offsets);
        stattn_sparse<<<dim3(Bb * (Tt / 16)), dim3(MTHREADS), 0, stream>>>(
            h_seq, sorted_t, sorted_idx, offsets, out);
    } else {
        stattn_kernel<<<dim3(Bb * (Tt / QB)), dim3(NTHREADS), 0, stream>>>(
            h_seq, tvals, out);
    }
}

// Round 4
// 22.867 us; speedup vs baseline: 22.1881x; 1.0327x over previous
//
#include <hip/hip_runtime.h>
#include <hip/hip_bf16.h>

// SoftTimeAttention: out[b,q,:] = sum_j softmax_j(-(T*(t_q-t_j))^2) * h[b,j,:]
// B=4, T=4096, H=256, f32. w = exp(-(4096*dt)^2) == 0 in f32 for |dt| > ~2.3e-3
// => ~19 active keys per query. Bucket-sort t (1024 buckets), process queries in
// sorted order; each wave shares one candidate window across QPW queries.

constexpr int Bb = 4;
constexpr int Tt = 4096;
constexpr int Hh = 256;
constexpr int NB = 1024;     // t-buckets per batch
// coverage: |dt| <= 2/1024 <=> w >= exp(-64); buckets [k-2, k+2] suffice.

// ---------------------------------------------------------------------------
// Per-batch counting sort. One block (1024 thr) per batch.
// Output: spair[b][pos] = { bitcast(t*4096), original_idx }, offsets[b][NB+1].
__global__ __launch_bounds__(1024) void sort_kernel(
    const float* __restrict__ tvals,
    uint2* __restrict__ spair,
    int* __restrict__ offsets)
{
    __shared__ int hist[NB];
    __shared__ int excl[NB];
    __shared__ int cnt[NB];
    __shared__ int wsum[16];
    __shared__ int wexcl[16];

    const int b    = blockIdx.x;
    const int tid  = threadIdx.x;
    const int lane = tid & 63;
    const int wv   = tid >> 6;
    const float* tb = tvals + (size_t)b * Tt;

    hist[tid] = 0;
    cnt[tid]  = 0;
    __syncthreads();

    float tv[4]; int bk[4];
    #pragma unroll
    for (int i = 0; i < 4; ++i) {
        const int j = i * 1024 + tid;
        const float t = tb[j];
        int k = (int)(t * (float)NB);
        k = k < 0 ? 0 : (k > NB - 1 ? NB - 1 : k);
        tv[i] = t * 4096.0f;      // pre-scaled for the main kernel
        bk[i] = k;
        atomicAdd(&hist[k], 1);
    }
    __syncthreads();

    // inclusive scan over 1024 buckets: wave scan + cross-wave fixup
    const int self = hist[tid];
    int x = self;
    #pragma unroll
    for (int d = 1; d < 64; d <<= 1) {
        const int y = __shfl_up(x, d);
        if (lane >= d) x += y;
    }
    if (lane == 63) wsum[wv] = x;
    __syncthreads();
    if (tid < 16) {
        int y = wsum[tid];
        #pragma unroll
        for (int d = 1; d < 16; d <<= 1) {
            const int z = __shfl_up(y, d);
            if (tid >= d) y += z;
        }
        wexcl[tid] = y - wsum[tid];
    }
    __syncthreads();
    const int incl = x + wexcl[wv];
    excl[tid] = incl - self;
    offsets[(size_t)b * (NB + 1) + tid] = incl - self;
    if (tid == 0) offsets[(size_t)b * (NB + 1) + NB] = Tt;
    __syncthreads();

    #pragma unroll
    for (int i = 0; i < 4; ++i) {
        const int k = bk[i];
        const int rank = atomicAdd(&cnt[k], 1);
        const int pos = excl[k] + rank;
        uint2 pr;
        pr.x = __float_as_uint(tv[i]);
        pr.y = (unsigned)(i * 1024 + tid);
        spair[(size_t)b * Tt + pos] = pr;
    }
}

// ---------------------------------------------------------------------------
// Main sparse kernel: 256 thr = 4 waves; each wave handles QPW=8 consecutive
// sorted queries (shared candidate window). Grid = B * T/32 = 512 blocks.
constexpr int QPW = 8;
constexpr int MTHREADS = 256;

__global__ __launch_bounds__(MTHREADS) void stattn_sparse(
    const float* __restrict__ h_seq,
    const uint2* __restrict__ spair,
    const int* __restrict__ offsets,
    float* __restrict__ out)
{
    const int tid  = threadIdx.x;
    const int lane = tid & 63;
    const int wv   = tid >> 6;

    // XCD-contiguous swizzle (512 blocks = 8 XCDs x 64): 2 XCDs per batch.
    const int phys = blockIdx.x;
    const int lb   = (phys & 7) * 64 + (phys >> 3);
    const int b    = lb >> 7;
    const int blk  = lb & 127;

    const uint2* sp  = spair + (size_t)b * Tt;
    const int*   off = offsets + (size_t)b * (NB + 1);
    const float* hb  = h_seq + (size_t)b * Tt * Hh;

    const int p0 = blk * 32 + wv * QPW;

    float tq[QPW]; int qi[QPW];
    #pragma unroll
    for (int g = 0; g < QPW; ++g) {
        const uint2 pr = sp[p0 + g];
        tq[g] = __uint_as_float(pr.x);     // t*4096
        qi[g] = (int)pr.y;
    }

    // candidate window (buckets nondecreasing along sorted positions)
    // bucket = floor(t*1024) = floor(ts * 0.25)
    int bmin = (int)(tq[0] * 0.25f);
    int bmax = (int)(tq[QPW - 1] * 0.25f);
    bmin = bmin < 0 ? 0 : (bmin > NB - 1 ? NB - 1 : bmin);
    bmax = bmax < 0 ? 0 : (bmax > NB - 1 ? NB - 1 : bmax);
    const int blo = bmin - 2 < 0 ? 0 : bmin - 2;
    const int bhi = bmax + 3 > NB ? NB : bmax + 3;
    const int lo = off[blo];
    const int hi = off[bhi];

    float4 acc[QPW];
    float  den[QPW];
    #pragma unroll
    for (int g = 0; g < QPW; ++g) {
        acc[g] = make_float4(0.f, 0.f, 0.f, 0.f);
        den[g] = 0.f;
    }

    for (int base = lo; base < hi; base += 64) {
        const int p = base + lane;
        const bool valid = p < hi;
        float tj; int jj;
        if (valid) { const uint2 pr = sp[p]; tj = __uint_as_float(pr.x); jj = (int)pr.y; }
        else       { tj = 3.0e18f; jj = 0; }   // -> w == 0 exactly

        float w[QPW]; float wmax = 0.f;
        #pragma unroll
        for (int g = 0; g < QPW; ++g) {
            const float x = tq[g] - tj;
            w[g] = __expf(-x * x);
            den[g] += w[g];
            wmax = fmaxf(wmax, w[g]);
        }

        unsigned long long mask = __ballot(wmax > 1e-20f);
        while (mask) {
            const int s0 = __builtin_ctzll(mask); mask &= mask - 1;
            const bool h1 = mask != 0;
            const int s1 = h1 ? __builtin_ctzll(mask) : s0; if (h1) mask &= mask - 1;
            const bool h2 = mask != 0;
            const int s2 = h2 ? __builtin_ctzll(mask) : s0; if (h2) mask &= mask - 1;
            const bool h3 = mask != 0;
            const int s3 = h3 ? __builtin_ctzll(mask) : s0; if (h3) mask &= mask - 1;

            const int j0 = __shfl(jj, s0);
            const int j1 = __shfl(jj, s1);
            const int j2 = __shfl(jj, s2);
            const int j3 = __shfl(jj, s3);
            float4 h0 = *(const float4*)&hb[(size_t)j0 * Hh + lane * 4];
            float4 h1v = *(const float4*)&hb[(size_t)j1 * Hh + lane * 4];
            float4 h2v = *(const float4*)&hb[(size_t)j2 * Hh + lane * 4];
            float4 h3v = *(const float4*)&hb[(size_t)j3 * Hh + lane * 4];
            // mask out duplicated slots once (amortized over all QPW queries)
            if (!h1) { h1v.x = 0.f; h1v.y = 0.f; h1v.z = 0.f; h1v.w = 0.f; }
            if (!h2) { h2v.x = 0.f; h2v.y = 0.f; h2v.z = 0.f; h2v.w = 0.f; }
            if (!h3) { h3v.x = 0.f; h3v.y = 0.f; h3v.z = 0.f; h3v.w = 0.f; }

            #pragma unroll
            for (int g = 0; g < QPW; ++g) {
                const float a0 = __shfl(w[g], s0);
                const float a1 = __shfl(w[g], s1);
                const float a2 = __shfl(w[g], s2);
                const float a3 = __shfl(w[g], s3);
                acc[g].x += a0 * h0.x; acc[g].y += a0 * h0.y;
                acc[g].z += a0 * h0.z; acc[g].w += a0 * h0.w;
                acc[g].x += a1 * h1v.x; acc[g].y += a1 * h1v.y;
                acc[g].z += a1 * h1v.z; acc[g].w += a1 * h1v.w;
                acc[g].x += a2 * h2v.x; acc[g].y += a2 * h2v.y;
                acc[g].z += a2 * h2v.z; acc[g].w += a2 * h2v.w;
                acc[g].x += a3 * h3v.x; acc[g].y += a3 * h3v.y;
                acc[g].z += a3 * h3v.z; acc[g].w += a3 * h3v.w;
            }
        }
    }

    // reduce denominators across lanes
    #pragma unroll
    for (int g = 0; g < QPW; ++g) {
        float d = den[g];
        #pragma unroll
        for (int s = 1; s < 64; s <<= 1) d += __shfl_xor(d, s);
        den[g] = d;
    }

    #pragma unroll
    for (int g = 0; g < QPW; ++g) {
        const float inv = 1.0f / den[g];
        float* orow = out + ((size_t)b * Tt + qi[g]) * Hh + lane * 4;
        float4 o;
        o.x = acc[g].x * inv; o.y = acc[g].y * inv;
        o.z = acc[g].z * inv; o.w = acc[g].w * inv;
        *(float4*)orow = o;
    }
}

// ---------------------------------------------------------------------------
// Fallback dense f32 kernel (round-1 proven) if ws is too small.
constexpr int QB = 64;
constexpr int JB = 64;
constexpr int NT = Tt / JB;
constexpr int NTHREADS = 512;

__device__ __forceinline__ void gld16(const void* g, void* l) {
    __builtin_amdgcn_global_load_lds(
        (const __attribute__((address_space(1))) void*)g,
        (__attribute__((address_space(3))) void*)l, 16, 0, 0);
}
__device__ __forceinline__ void gld4(const void* g, void* l) {
    __builtin_amdgcn_global_load_lds(
        (const __attribute__((address_space(1))) void*)g,
        (__attribute__((address_space(3))) void*)l, 4, 0, 0);
}

__global__ __launch_bounds__(NTHREADS, 2) void stattn_kernel(
    const float* __restrict__ h_seq,
    const float* __restrict__ tvals,
    float* __restrict__ out)
{
    __shared__ float hbuf[2][JB][Hh];
    __shared__ float wbuf[JB][QB];
    __shared__ float tjbuf[2][JB];
    __shared__ float sden[QB];
    __shared__ float tqs[QB];

    const int tid  = threadIdx.x;
    const int lane = tid & 63;
    const int wv   = tid >> 6;
    const int phys = blockIdx.x;
    const int lb   = (phys & 7) * 32 + (phys >> 3);
    const int b    = lb >> 6;
    const int qt   = lb & 63;
    const int q0   = qt * QB;

    const float* hb = h_seq + (size_t)b * Tt * Hh;
    const float* tb = tvals + (size_t)b * Tt;

    if (tid < QB) { tqs[tid] = tb[q0 + tid]; sden[tid] = 0.0f; }

    float acc[8][4];
    #pragma unroll
    for (int k = 0; k < 8; ++k)
        #pragma unroll
        for (int c = 0; c < 4; ++c) acc[k][c] = 0.0f;

    const float Tf = (float)Tt;

    auto stage = [&](int buf, int tile) {
        const float* src = hb + (size_t)tile * JB * Hh;
        float* dst = &hbuf[buf][0][0];
        #pragma unroll
        for (int i = 0; i < 8; ++i) {
            const int off = i * (NTHREADS * 4) + tid * 4;
            gld16(src + off, dst + off);
        }
        gld4(tb + tile * JB + lane, &tjbuf[buf][lane]);
    };

    stage(0, 0);
    __syncthreads();

    const int qw = wv * 8;

    for (int t = 0; t < NT; ++t) {
        const int cur = t & 1;
        __syncthreads();
        {
            const int q  = tid & 63;
            const int jg = tid >> 6;
            const float tqv = tqs[q];
            const float4 tj0 = *(const float4*)&tjbuf[cur][jg * 8];
            const float4 tj1 = *(const float4*)&tjbuf[cur][jg * 8 + 4];
            const float tjv[8] = {tj0.x, tj0.y, tj0.z, tj0.w,
                                  tj1.x, tj1.y, tj1.z, tj1.w};
            float part = 0.0f;
            #pragma unroll
            for (int jj = 0; jj < 8; ++jj) {
                const float d = Tf * (tqv - tjv[jj]);
                const float w = __expf(-d * d);
                wbuf[jg * 8 + jj][q] = w;
                part += w;
            }
            atomicAdd(&sden[q], part);
        }
        if (t + 1 < NT) stage((t + 1) & 1, t + 1);
        asm volatile("s_waitcnt lgkmcnt(0)" ::: "memory");
        __builtin_amdgcn_s_barrier();
        asm volatile("" ::: "memory");
        #pragma unroll 2
        for (int j = 0; j < JB; ++j) {
            const float4 hv = *(const float4*)&hbuf[cur][j][lane * 4];
            const float4 w0 = *(const float4*)&wbuf[j][qw];
            const float4 w1 = *(const float4*)&wbuf[j][qw + 4];
            const float wr[8] = {w0.x, w0.y, w0.z, w0.w,
                                 w1.x, w1.y, w1.z, w1.w};
            #pragma unroll
            for (int k = 0; k < 8; ++k) {
                acc[k][0] += wr[k] * hv.x;
                acc[k][1] += wr[k] * hv.y;
                acc[k][2] += wr[k] * hv.z;
                acc[k][3] += wr[k] * hv.w;
            }
        }
    }

    #pragma unroll
    for (int k = 0; k < 8; ++k) {
        const int q = q0 + qw + k;
        const float inv = 1.0f / sden[qw + k];
        float4 o;
        o.x = acc[k][0] * inv;
        o.y = acc[k][1] * inv;
        o.z = acc[k][2] * inv;
        o.w = acc[k][3] * inv;
        *(float4*)&out[((size_t)b * Tt + q) * Hh + (size_t)(lane * 4)] = o;
    }
}

extern "C" void kernel_launch(void* const* d_in, const int* in_sizes, int n_in,
                              void* d_out, int out_size, void* d_ws, size_t ws_size,
                              hipStream_t stream) {
    const float* h_seq = (const float*)d_in[0];
    const float* tvals = (const float*)d_in[1];
    float* out = (float*)d_out;

    // ws layout: spair (B*T uint2) | offsets (B*(NB+1) i32)
    const size_t need = (size_t)Bb * Tt * sizeof(uint2) + (size_t)Bb * (NB + 1) * 4;
    if (ws_size >= need) {
        uint2* spair  = (uint2*)d_ws;
        int*   offsets = (int*)(spair + (size_t)Bb * Tt);
        sort_kernel<<<dim3(Bb), dim3(1024), 0, stream>>>(tvals, spair, offsets);
        stattn_sparse<<<dim3(Bb * (Tt / 32)), dim3(MTHREADS), 0, stream>>>(
            h_seq, spair, offsets, out);
    } else {
        stattn_kernel<<<dim3(Bb * (Tt / QB)), dim3(NTHREADS), 0, stream>>>(
            h_seq, tvals, out);
    }
}